// Round 5
// baseline (388.818 us; speedup 1.0000x reference)
//
#include <hip/hip_runtime.h>
#include <hip/hip_bf16.h>

#define BSZ   8
#define SEQ   1024
#define EMB   1024
#define NH    16
#define HD    64
#define MROWS (BSZ*SEQ)   // 8192
#define LOG2E 1.44269504088896f

typedef short  short8  __attribute__((ext_vector_type(8)));
typedef short  short4v __attribute__((ext_vector_type(4)));
typedef float  floatx4 __attribute__((ext_vector_type(4)));
typedef unsigned int uint2v __attribute__((ext_vector_type(2)));
typedef unsigned int uint4v __attribute__((ext_vector_type(4)));

__device__ __forceinline__ unsigned short f2bf(float f) {
  union { float f; unsigned u; } v; v.f = f;
  unsigned r = v.u + 0x7FFFu + ((v.u >> 16) & 1u);   // RNE
  return (unsigned short)(r >> 16);
}
__device__ __forceinline__ unsigned pk2bf(float a, float b) {
  __hip_bfloat162 t = __float22bfloat162_rn(make_float2(a, b));
  union { __hip_bfloat162 h; unsigned u; } c; c.h = t; return c.u;  // .x in low 16
}

// async global->LDS, 16B/lane; LDS dest = wave-uniform base + lane*16
__device__ __forceinline__ void g2lds16(const unsigned short* g, unsigned short* l) {
  __builtin_amdgcn_global_load_lds(
      (const __attribute__((address_space(1))) unsigned int*)g,
      (__attribute__((address_space(3))) unsigned int*)l, 16, 0, 0);
}

// ---------------- batched weight convert: z in 0..3 -----------------------
__global__ __launch_bounds__(256) void convert_w4(
    const float* __restrict__ w0, const float* __restrict__ w1,
    const float* __restrict__ w2, const float* __restrict__ w3,
    unsigned short* __restrict__ out, float qs)
{
  const int z = blockIdx.y;
  const float* w = (z == 0) ? w0 : (z == 1) ? w1 : (z == 2) ? w2 : w3;
  const float s = (z == 0) ? qs : 1.0f;
  int i = blockIdx.x * 256 + threadIdx.x;
  float4 f = ((const float4*)w)[i];
  short4v p;
  p.x = (short)f2bf(f.x * s); p.y = (short)f2bf(f.y * s);
  p.z = (short)f2bf(f.z * s); p.w = (short)f2bf(f.w * s);
  ((short4v*)(out + (size_t)z * EMB * EMB))[i] = p;
}

// ---------------- GEMM: C[M,N] = A[M,K] @ W[N,K]^T + bias -----------------
// Double-buffered LDS, single barrier per K-tile.
// QKV=1: z-batched {query,key,value} fp32 A (reg-staged convert);
//        out bf16: z<2 -> [b][h][s][d] scatter; z==2 -> [b][h][d][s] packed 8B.
// QKV=0: A bf16 via global_load_lds, out fp32 [M][N].
// LDS XOR-swizzle: logical 16B chunk c of row r stored at chunk c^(r&7).
template<int QKV>
__global__ __launch_bounds__(256, 2) void gemm_k(
    const float* __restrict__ A0, const float* __restrict__ A1,
    const float* __restrict__ A2,
    const unsigned short* __restrict__ Abf,
    const unsigned short* __restrict__ Wbase,
    const float* __restrict__ b0, const float* __restrict__ b1,
    const float* __restrict__ b2, float qs,
    unsigned short* __restrict__ obf, float* __restrict__ of32)
{
  __shared__ __align__(16) unsigned short As[2][128 * 64];
  __shared__ __align__(16) unsigned short Ws[2][128 * 64];
  const int tid  = threadIdx.x;
  const int lane = tid & 63, wid = tid >> 6;
  const int z    = QKV ? blockIdx.z : 0;
  const int n0   = blockIdx.x * 128;
  const int m0   = blockIdx.y * 128;
  const int wm = (wid & 1) * 64, wn = (wid >> 1) * 64;
  const int quad = lane >> 4, ln = lane & 15, e3 = ln & 7;
  const int lrow = lane >> 3;
  const int lcol8 = ((lane & 7) ^ lrow) * 8;

  const unsigned short* W = Wbase + (size_t)z * EMB * EMB;
  const float* Af = QKV ? ((z == 0) ? A0 : (z == 1) ? A1 : A2) : (const float*)0;
  const int ar = tid >> 1;                        // A-staging row (QKV)
  const int ac = (tid & 1) * 32;                  // f32 col base

  floatx4 acc[4][4] = {};
  float4 ax[8];

  // ---- prologue: tile 0 into buf 0
  if (QKV) {
    const float* src = Af + (size_t)(m0 + ar) * EMB + ac;
#pragma unroll
    for (int i = 0; i < 8; i++) ax[i] = *(const float4*)(src + i * 4);
  }
#pragma unroll
  for (int c = 0; c < 4; c++) {
    int r = wid * 32 + c * 8;
    g2lds16(W + (size_t)(n0 + r + lrow) * EMB + lcol8, &Ws[0][r * 64]);
    if (!QKV) g2lds16(Abf + (size_t)(m0 + r + lrow) * EMB + lcol8, &As[0][r * 64]);
  }
  if (QKV) {
#pragma unroll
    for (int i = 0; i < 4; i++) {
      uint4v u;
      u.x = pk2bf(ax[2*i].x, ax[2*i].y);     u.y = pk2bf(ax[2*i].z, ax[2*i].w);
      u.z = pk2bf(ax[2*i+1].x, ax[2*i+1].y); u.w = pk2bf(ax[2*i+1].z, ax[2*i+1].w);
      int ch = (4 * (tid & 1) + i) ^ (ar & 7);
      *(uint4v*)&As[0][ar * 64 + ch * 8] = u;
    }
  }

  const int NK = EMB / 64;
  for (int it = 0; it < NK; ++it) {
    __syncthreads();                       // publishes buf[it&1]
    const int cb = it & 1, nb = (it + 1) & 1;
    if (it < NK - 1) {
      const int k1 = (it + 1) * 64;
      if (QKV) {
        const float* src = Af + (size_t)(m0 + ar) * EMB + k1 + ac;
#pragma unroll
        for (int i = 0; i < 8; i++) ax[i] = *(const float4*)(src + i * 4);
      }
#pragma unroll
      for (int c = 0; c < 4; c++) {
        int r = wid * 32 + c * 8;
        g2lds16(W + (size_t)(n0 + r + lrow) * EMB + k1 + lcol8, &Ws[nb][r * 64]);
        if (!QKV) g2lds16(Abf + (size_t)(m0 + r + lrow) * EMB + k1 + lcol8, &As[nb][r * 64]);
      }
    }
#pragma unroll
    for (int ks = 0; ks < 2; ks++) {
      short8 af[4], wf[4];
#pragma unroll
      for (int t = 0; t < 4; t++) {
        int pc = ((4 * ks + quad) ^ e3) * 8;
        af[t] = *(const short8*)&As[cb][(wm + t * 16 + ln) * 64 + pc];
        wf[t] = *(const short8*)&Ws[cb][(wn + t * 16 + ln) * 64 + pc];
      }
#pragma unroll
      for (int mi = 0; mi < 4; mi++)
#pragma unroll
        for (int ni = 0; ni < 4; ni++)
          acc[mi][ni] = __builtin_amdgcn_mfma_f32_16x16x32_bf16(
              af[mi], wf[ni], acc[mi][ni], 0, 0, 0);
    }
    if (QKV && it < NK - 1) {
#pragma unroll
      for (int i = 0; i < 4; i++) {
        uint4v u;
        u.x = pk2bf(ax[2*i].x, ax[2*i].y);     u.y = pk2bf(ax[2*i].z, ax[2*i].w);
        u.z = pk2bf(ax[2*i+1].x, ax[2*i+1].y); u.w = pk2bf(ax[2*i+1].z, ax[2*i+1].w);
        int ch = (4 * (tid & 1) + i) ^ (ar & 7);
        *(uint4v*)&As[nb][ar * 64 + ch * 8] = u;
      }
    }
  }

  const float* bias = QKV ? ((z == 0) ? b0 : (z == 1) ? b1 : b2) : b0;
  const float bsc = (QKV && z == 0) ? qs : 1.0f;
  unsigned short* outz = obf + (size_t)z * MROWS * EMB;

#pragma unroll
  for (int mi = 0; mi < 4; mi++) {
#pragma unroll
    for (int ni = 0; ni < 4; ni++) {
      int gn = n0 + wn + ni * 16 + ln;
      float bv = bsc * bias[gn];
      int gmb = m0 + wm + mi * 16 + quad * 4;
      if (!QKV) {
#pragma unroll
        for (int r = 0; r < 4; r++)
          of32[(size_t)(gmb + r) * EMB + gn] = acc[mi][ni][r] + bv;
      } else if (z < 2) {
        int h = gn >> 6, d = gn & 63;
#pragma unroll
        for (int r = 0; r < 4; r++) {
          int gm = gmb + r;
          int b = gm >> 10, s = gm & 1023;
          outz[((size_t)(b * NH + h) * SEQ + s) * HD + d] = f2bf(acc[mi][ni][r] + bv);
        }
      } else {
        int h = gn >> 6, d = gn & 63;
        int b = gmb >> 10, s = gmb & 1023;
        short4v pkt;
        pkt.x = (short)f2bf(acc[mi][ni][0] + bv);
        pkt.y = (short)f2bf(acc[mi][ni][1] + bv);
        pkt.z = (short)f2bf(acc[mi][ni][2] + bv);
        pkt.w = (short)f2bf(acc[mi][ni][3] + bv);
        *(short4v*)&outz[((size_t)(b * NH + h) * HD + d) * SEQ + s] = pkt;
      }
    }
  }
}

// ---------------- flash attention v5 --------------------------------------
// Block = 4 waves, 256 Q-rows (4 t-subtiles/wave). S^T = K*Q^T, no-max
// base-2 softmax. K/V double-buffered in LDS (one barrier per s-tile);
// K/V fragments hoisted to registers, reused across 4 subtiles.
// Row-sums via ones-row MFMA. O^T packed 8B stores.
__global__ __launch_bounds__(256, 2) void attn_k(
    const unsigned short* __restrict__ q,    // [BH][S][D]
    const unsigned short* __restrict__ k,    // [BH][S][D]
    const unsigned short* __restrict__ vt,   // [BH][D][S]
    unsigned short* __restrict__ o)          // [B][S][E] bf16
{
  __shared__ __align__(16) unsigned short Ks[2][64 * 64];   // [s][d] swizzled
  __shared__ __align__(16) unsigned short Vs[2][64 * 64];   // [d][s] swizzled
  __shared__ __align__(16) unsigned short Pb[4][16][72];    // [wave][t][s]
  const int tid  = threadIdx.x;
  const int lane = tid & 63, wv = tid >> 6;
  const int quad = lane >> 4, ln = lane & 15, e3 = ln & 7;
  const int bh = blockIdx.x >> 2;
  const int tb = (blockIdx.x & 3) * 256;
  const int b = bh >> 4, h = bh & 15;
  const int lrow = lane >> 3;
  const int lcol8 = ((lane & 7) ^ lrow) * 8;

  const unsigned short* qh = q  + (size_t)bh * SEQ * HD;
  const unsigned short* kh = k  + (size_t)bh * SEQ * HD;
  const unsigned short* vh = vt + (size_t)bh * HD * SEQ;

  // Q as B-operand: B[n=ln -> t][k=quad*8+j -> d], 4 subtiles
  short8 qf[4][2];
#pragma unroll
  for (int tt = 0; tt < 4; tt++)
#pragma unroll
    for (int kc = 0; kc < 2; kc++)
      qf[tt][kc] = *(const short8*)(qh +
          (size_t)(tb + tt * 64 + wv * 16 + ln) * HD + kc * 32 + quad * 8);

  const short ONE = (short)0x3F80;
  const short8 onesf = {ONE, ONE, ONE, ONE, ONE, ONE, ONE, ONE};

  floatx4 Oa[4][4] = {};   // [subtile][d-tile] O^T
  floatx4 Ol[4]    = {};   // row-sums per subtile

  // prologue: stage s-tile 0 into buf 0
#pragma unroll
  for (int c = 0; c < 2; c++) {
    int ch = wv * 2 + c;
    g2lds16(kh + (size_t)(ch * 8 + lrow) * HD + lcol8,  &Ks[0][ch * 8 * 64]);
    g2lds16(vh + (size_t)(ch * 8 + lrow) * SEQ + lcol8, &Vs[0][ch * 8 * 64]);
  }

  for (int it = 0; it < SEQ / 64; ++it) {
    __syncthreads();                      // publishes buf[it&1]
    const int cb = it & 1, nb = (it + 1) & 1;
    if (it < SEQ / 64 - 1) {
      const int s1 = (it + 1) * 64;
#pragma unroll
      for (int c = 0; c < 2; c++) {
        int ch = wv * 2 + c;
        g2lds16(kh + (size_t)(s1 + ch * 8 + lrow) * HD + lcol8,  &Ks[nb][ch * 8 * 64]);
        g2lds16(vh + (size_t)(ch * 8 + lrow) * SEQ + s1 + lcol8, &Vs[nb][ch * 8 * 64]);
      }
    }

    // hoist K/V fragments (reused by all 4 subtiles)
    short8 kf[4][2], vf[4][2];
#pragma unroll
    for (int st = 0; st < 4; st++) {
      kf[st][0] = *(const short8*)&Ks[cb][(st * 16 + ln) * 64 + ((0 + quad) ^ e3) * 8];
      kf[st][1] = *(const short8*)&Ks[cb][(st * 16 + ln) * 64 + ((4 + quad) ^ e3) * 8];
      vf[st][0] = *(const short8*)&Vs[cb][(st * 16 + ln) * 64 + ((0 + quad) ^ e3) * 8];
      vf[st][1] = *(const short8*)&Vs[cb][(st * 16 + ln) * 64 + ((4 + quad) ^ e3) * 8];
    }

#pragma unroll
    for (int tt = 0; tt < 4; tt++) {
      floatx4 sc[4];
#pragma unroll
      for (int st = 0; st < 4; st++) {
        floatx4 a = {};
        a = __builtin_amdgcn_mfma_f32_16x16x32_bf16(kf[st][0], qf[tt][0], a, 0, 0, 0);
        a = __builtin_amdgcn_mfma_f32_16x16x32_bf16(kf[st][1], qf[tt][1], a, 0, 0, 0);
        sc[st] = a;
      }
      // P^T = exp2(S^T): 4 regs = consecutive s-cols of row t=ln -> b64 write
#pragma unroll
      for (int st = 0; st < 4; st++) {
        uint2v u;
        u.x = pk2bf(exp2f(sc[st][0]), exp2f(sc[st][1]));
        u.y = pk2bf(exp2f(sc[st][2]), exp2f(sc[st][3]));
        *(uint2v*)&Pb[wv][ln][st * 16 + quad * 4] = u;
      }
      // P @ V (same-wave in-order LDS: read sees this wave's writes)
#pragma unroll
      for (int kc = 0; kc < 2; kc++) {
        short8 pf = *(const short8*)&Pb[wv][ln][kc * 32 + quad * 8];
#pragma unroll
        for (int di = 0; di < 4; di++)
          Oa[tt][di] = __builtin_amdgcn_mfma_f32_16x16x32_bf16(vf[di][kc], pf, Oa[tt][di], 0, 0, 0);
        Ol[tt] = __builtin_amdgcn_mfma_f32_16x16x32_bf16(onesf, pf, Ol[tt], 0, 0, 0);
      }
    }
  }

  // epilogue: O^T[d = di*16+quad*4+r][t = ln] per subtile
#pragma unroll
  for (int tt = 0; tt < 4; tt++) {
    float linv = 1.0f / Ol[tt][0];
    size_t rowbase = (size_t)(b * SEQ + tb + tt * 64 + wv * 16 + ln) * EMB + h * HD;
#pragma unroll
    for (int di = 0; di < 4; di++) {
      uint2v pkt;
      pkt.x = pk2bf(Oa[tt][di][0] * linv, Oa[tt][di][1] * linv);
      pkt.y = pk2bf(Oa[tt][di][2] * linv, Oa[tt][di][3] * linv);
      *(uint2v*)&o[rowbase + di * 16 + quad * 4] = pkt;
    }
  }
}

// ---------------- launch --------------------------------------------------
extern "C" void kernel_launch(void* const* d_in, const int* in_sizes, int n_in,
                              void* d_out, int out_size, void* d_ws, size_t ws_size,
                              hipStream_t stream) {
  const float* query = (const float*)d_in[0];
  const float* key   = (const float*)d_in[1];
  const float* value = (const float*)d_in[2];
  const float* Wq = (const float*)d_in[3];
  const float* bq = (const float*)d_in[4];
  const float* Wk = (const float*)d_in[5];
  const float* bk = (const float*)d_in[6];
  const float* Wv = (const float*)d_in[7];
  const float* bv = (const float*)d_in[8];
  const float* Wo = (const float*)d_in[9];
  const float* bo = (const float*)d_in[10];
  float* out = (float*)d_out;

  unsigned short* ws = (unsigned short*)d_ws;
  const size_t WSZ = (size_t)EMB * EMB;     // 1M elems
  const size_t TSZ = (size_t)MROWS * EMB;   // 8M elems
  unsigned short* Wb   = ws;                // [4][N][K] bf16 (q,k,v,o)
  unsigned short* q_b  = Wb + 4 * WSZ;      // qkv outputs contiguous (z-indexed)
  unsigned short* k_b  = q_b + TSZ;
  unsigned short* vt_b = k_b + TSZ;
  unsigned short* o_b  = vt_b + TSZ;

  const float qscale = 0.125f * LOG2E;      // head_dim^-0.5 * log2(e)

  convert_w4<<<dim3((int)(WSZ / 4 / 256), 4), 256, 0, stream>>>(Wq, Wk, Wv, Wo, Wb, qscale);

  gemm_k<1><<<dim3(EMB / 128, MROWS / 128, 3), 256, 0, stream>>>(
      query, key, value, (const unsigned short*)0, Wb,
      bq, bk, bv, qscale, q_b, (float*)0);

  attn_k<<<dim3(BSZ * NH * (SEQ / 256)), 256, 0, stream>>>(q_b, k_b, vt_b, o_b);

  gemm_k<0><<<dim3(EMB / 128, MROWS / 128, 1), 256, 0, stream>>>(
      (const float*)0, (const float*)0, (const float*)0, o_b, Wb + 3 * WSZ,
      bo, (const float*)0, (const float*)0, 1.0f, (unsigned short*)0, out);
}

// Round 6
// 348.542 us; speedup vs baseline: 1.1156x; 1.1156x over previous
//
#include <hip/hip_runtime.h>
#include <hip/hip_bf16.h>

#define BSZ   8
#define SEQ   1024
#define EMB   1024
#define NH    16
#define HD    64
#define MROWS (BSZ*SEQ)   // 8192
#define LOG2E 1.44269504088896f

typedef short  short8  __attribute__((ext_vector_type(8)));
typedef short  short4v __attribute__((ext_vector_type(4)));
typedef float  floatx4 __attribute__((ext_vector_type(4)));
typedef unsigned int uint2v __attribute__((ext_vector_type(2)));
typedef unsigned int uint4v __attribute__((ext_vector_type(4)));

__device__ __forceinline__ unsigned short f2bf(float f) {
  union { float f; unsigned u; } v; v.f = f;
  unsigned r = v.u + 0x7FFFu + ((v.u >> 16) & 1u);   // RNE
  return (unsigned short)(r >> 16);
}
__device__ __forceinline__ unsigned pk2bf(float a, float b) {
  __hip_bfloat162 t = __float22bfloat162_rn(make_float2(a, b));
  union { __hip_bfloat162 h; unsigned u; } c; c.h = t; return c.u;  // .x in low 16
}

// async global->LDS, 16B/lane; LDS dest = wave-uniform base + lane*16
__device__ __forceinline__ void g2lds16(const unsigned short* g, unsigned short* l) {
  __builtin_amdgcn_global_load_lds(
      (const __attribute__((address_space(1))) unsigned int*)g,
      (__attribute__((address_space(3))) unsigned int*)l, 16, 0, 0);
}

// ---------------- batched weight convert: z in 0..3 -----------------------
__global__ __launch_bounds__(256) void convert_w4(
    const float* __restrict__ w0, const float* __restrict__ w1,
    const float* __restrict__ w2, const float* __restrict__ w3,
    unsigned short* __restrict__ out, float qs)
{
  const int z = blockIdx.y;
  const float* w = (z == 0) ? w0 : (z == 1) ? w1 : (z == 2) ? w2 : w3;
  const float s = (z == 0) ? qs : 1.0f;
  int i = blockIdx.x * 256 + threadIdx.x;
  float4 f = ((const float4*)w)[i];
  short4v p;
  p.x = (short)f2bf(f.x * s); p.y = (short)f2bf(f.y * s);
  p.z = (short)f2bf(f.z * s); p.w = (short)f2bf(f.w * s);
  ((short4v*)(out + (size_t)z * EMB * EMB))[i] = p;
}

// ---------------- GEMM: C[M,N] = A[M,K] @ W[N,K]^T + bias -----------------
// Single-buffer LDS (dbuf measured neutral: m99/m100 + round-5 A/B).
// 1D grid, XCD-aware swizzle: xcd = j&7 pinned; n cycles fastest among
// same-XCD blocks so the 8 n-blocks sharing an A-tile are co-resident on
// one XCD (A-tile hits L2); z slowest (one 32MB input active for L3).
// QKV=1: z-batched {query,key,value} fp32 A (reg-staged convert);
//        out bf16: z<2 -> [b][h][s][d] scatter; z==2 -> [b][h][d][s] packed 8B.
// QKV=0: A bf16 via global_load_lds, out fp32 [M][N].
// LDS XOR-swizzle: logical 16B chunk c of row r stored at chunk c^(r&7).
template<int QKV>
__global__ __launch_bounds__(256, 2) void gemm_k(
    const float* __restrict__ A0, const float* __restrict__ A1,
    const float* __restrict__ A2,
    const unsigned short* __restrict__ Abf,
    const unsigned short* __restrict__ Wbase,
    const float* __restrict__ b0, const float* __restrict__ b1,
    const float* __restrict__ b2, float qs,
    unsigned short* __restrict__ obf, float* __restrict__ of32)
{
  __shared__ __align__(16) unsigned short As[128 * 64];
  __shared__ __align__(16) unsigned short Ws[128 * 64];
  const int tid  = threadIdx.x;
  const int lane = tid & 63, wid = tid >> 6;

  // XCD-aware decode
  const int j    = blockIdx.x;
  const int xcd  = j & 7;
  const int rest = j >> 3;
  const int nb   = rest & 7;
  int z, mrow;
  if (QKV) { int mz = rest >> 3; mrow = xcd + 8 * (mz & 7); z = mz >> 3; }
  else     { mrow = xcd + 8 * (rest >> 3); z = 0; }
  const int n0 = nb * 128;
  const int m0 = mrow * 128;

  const int wm = (wid & 1) * 64, wn = (wid >> 1) * 64;
  const int quad = lane >> 4, ln = lane & 15, e3 = ln & 7;
  const int lrow = lane >> 3;
  const int lcol8 = ((lane & 7) ^ lrow) * 8;

  const unsigned short* W = Wbase + (size_t)z * EMB * EMB;
  const float* Af = QKV ? ((z == 0) ? A0 : (z == 1) ? A1 : A2) : (const float*)0;
  const int ar = tid >> 1;                        // A-staging row (QKV)
  const int ac = (tid & 1) * 32;                  // f32 col base

  floatx4 acc[4][4] = {};

  for (int k0 = 0; k0 < EMB; k0 += 64) {
    if (QKV) {
      const float* src = Af + (size_t)(m0 + ar) * EMB + k0 + ac;
#pragma unroll
      for (int i = 0; i < 4; i++) {
        float4 x = *(const float4*)(src + i * 8);
        float4 y = *(const float4*)(src + i * 8 + 4);
        uint4v u;
        u.x = pk2bf(x.x, x.y); u.y = pk2bf(x.z, x.w);
        u.z = pk2bf(y.x, y.y); u.w = pk2bf(y.z, y.w);
        int ch = (4 * (tid & 1) + i) ^ (ar & 7);
        *(uint4v*)&As[ar * 64 + ch * 8] = u;
      }
#pragma unroll
      for (int c = 0; c < 4; c++) {
        int r = wid * 32 + c * 8;
        g2lds16(W + (size_t)(n0 + r + lrow) * EMB + k0 + lcol8, &Ws[r * 64]);
      }
    } else {
#pragma unroll
      for (int c = 0; c < 4; c++) {
        int r = wid * 32 + c * 8;
        g2lds16(Abf + (size_t)(m0 + r + lrow) * EMB + k0 + lcol8, &As[r * 64]);
        g2lds16(W   + (size_t)(n0 + r + lrow) * EMB + k0 + lcol8, &Ws[r * 64]);
      }
    }
    __syncthreads();
#pragma unroll
    for (int ks = 0; ks < 2; ks++) {
      short8 af[4], wf[4];
#pragma unroll
      for (int t = 0; t < 4; t++) {
        int pc = ((4 * ks + quad) ^ e3) * 8;
        af[t] = *(const short8*)&As[(wm + t * 16 + ln) * 64 + pc];
        wf[t] = *(const short8*)&Ws[(wn + t * 16 + ln) * 64 + pc];
      }
#pragma unroll
      for (int mi = 0; mi < 4; mi++)
#pragma unroll
        for (int ni = 0; ni < 4; ni++)
          acc[mi][ni] = __builtin_amdgcn_mfma_f32_16x16x32_bf16(
              af[mi], wf[ni], acc[mi][ni], 0, 0, 0);
    }
    __syncthreads();
  }

  const float* bias = QKV ? ((z == 0) ? b0 : (z == 1) ? b1 : b2) : b0;
  const float bsc = (QKV && z == 0) ? qs : 1.0f;
  unsigned short* outz = obf + (size_t)z * MROWS * EMB;

#pragma unroll
  for (int mi = 0; mi < 4; mi++) {
#pragma unroll
    for (int ni = 0; ni < 4; ni++) {
      int gn = n0 + wn + ni * 16 + ln;
      float bv = bsc * bias[gn];
      int gmb = m0 + wm + mi * 16 + quad * 4;
      if (!QKV) {
#pragma unroll
        for (int r = 0; r < 4; r++)
          of32[(size_t)(gmb + r) * EMB + gn] = acc[mi][ni][r] + bv;
      } else if (z < 2) {
        int h = gn >> 6, d = gn & 63;
#pragma unroll
        for (int r = 0; r < 4; r++) {
          int gm = gmb + r;
          int b = gm >> 10, s = gm & 1023;
          outz[((size_t)(b * NH + h) * SEQ + s) * HD + d] = f2bf(acc[mi][ni][r] + bv);
        }
      } else {
        int h = gn >> 6, d = gn & 63;
        int b = gmb >> 10, s = gmb & 1023;
        short4v pkt;
        pkt.x = (short)f2bf(acc[mi][ni][0] + bv);
        pkt.y = (short)f2bf(acc[mi][ni][1] + bv);
        pkt.z = (short)f2bf(acc[mi][ni][2] + bv);
        pkt.w = (short)f2bf(acc[mi][ni][3] + bv);
        *(short4v*)&outz[((size_t)(b * NH + h) * HD + d) * SEQ + s] = pkt;
      }
    }
  }
}

// ---------------- flash attention v5 + XCD swizzle ------------------------
// Block = 4 waves, 256 Q-rows (4 t-subtiles/wave). S^T = K*Q^T, no-max
// base-2 softmax. K/V double-buffered in LDS (one barrier per s-tile);
// K/V fragments hoisted to registers, reused across 4 subtiles.
// 4 t-blocks of one (b,h) co-resident on one XCD (K/V head hits L2).
__global__ __launch_bounds__(256, 2) void attn_k(
    const unsigned short* __restrict__ q,    // [BH][S][D]
    const unsigned short* __restrict__ k,    // [BH][S][D]
    const unsigned short* __restrict__ vt,   // [BH][D][S]
    unsigned short* __restrict__ o)          // [B][S][E] bf16
{
  __shared__ __align__(16) unsigned short Ks[2][64 * 64];   // [s][d] swizzled
  __shared__ __align__(16) unsigned short Vs[2][64 * 64];   // [d][s] swizzled
  __shared__ __align__(16) unsigned short Pb[4][16][72];    // [wave][t][s]
  const int tid  = threadIdx.x;
  const int lane = tid & 63, wv = tid >> 6;
  const int quad = lane >> 4, ln = lane & 15, e3 = ln & 7;

  const int j    = blockIdx.x;
  const int rest = j >> 3;
  const int bh   = (j & 7) + 8 * (rest >> 2);
  const int tb   = (rest & 3) * 256;

  const int b = bh >> 4, h = bh & 15;
  const int lrow = lane >> 3;
  const int lcol8 = ((lane & 7) ^ lrow) * 8;

  const unsigned short* qh = q  + (size_t)bh * SEQ * HD;
  const unsigned short* kh = k  + (size_t)bh * SEQ * HD;
  const unsigned short* vh = vt + (size_t)bh * HD * SEQ;

  // Q as B-operand: B[n=ln -> t][k=quad*8+j -> d], 4 subtiles
  short8 qf[4][2];
#pragma unroll
  for (int tt = 0; tt < 4; tt++)
#pragma unroll
    for (int kc = 0; kc < 2; kc++)
      qf[tt][kc] = *(const short8*)(qh +
          (size_t)(tb + tt * 64 + wv * 16 + ln) * HD + kc * 32 + quad * 8);

  const short ONE = (short)0x3F80;
  const short8 onesf = {ONE, ONE, ONE, ONE, ONE, ONE, ONE, ONE};

  floatx4 Oa[4][4] = {};   // [subtile][d-tile] O^T
  floatx4 Ol[4]    = {};   // row-sums per subtile

  // prologue: stage s-tile 0 into buf 0
#pragma unroll
  for (int c = 0; c < 2; c++) {
    int ch = wv * 2 + c;
    g2lds16(kh + (size_t)(ch * 8 + lrow) * HD + lcol8,  &Ks[0][ch * 8 * 64]);
    g2lds16(vh + (size_t)(ch * 8 + lrow) * SEQ + lcol8, &Vs[0][ch * 8 * 64]);
  }

  for (int it = 0; it < SEQ / 64; ++it) {
    __syncthreads();                      // publishes buf[it&1]
    const int cb = it & 1, nbuf = (it + 1) & 1;
    if (it < SEQ / 64 - 1) {
      const int s1 = (it + 1) * 64;
#pragma unroll
      for (int c = 0; c < 2; c++) {
        int ch = wv * 2 + c;
        g2lds16(kh + (size_t)(s1 + ch * 8 + lrow) * HD + lcol8,  &Ks[nbuf][ch * 8 * 64]);
        g2lds16(vh + (size_t)(ch * 8 + lrow) * SEQ + s1 + lcol8, &Vs[nbuf][ch * 8 * 64]);
      }
    }

    // hoist K/V fragments (reused by all 4 subtiles)
    short8 kf[4][2], vf[4][2];
#pragma unroll
    for (int st = 0; st < 4; st++) {
      kf[st][0] = *(const short8*)&Ks[cb][(st * 16 + ln) * 64 + ((0 + quad) ^ e3) * 8];
      kf[st][1] = *(const short8*)&Ks[cb][(st * 16 + ln) * 64 + ((4 + quad) ^ e3) * 8];
      vf[st][0] = *(const short8*)&Vs[cb][(st * 16 + ln) * 64 + ((0 + quad) ^ e3) * 8];
      vf[st][1] = *(const short8*)&Vs[cb][(st * 16 + ln) * 64 + ((4 + quad) ^ e3) * 8];
    }

#pragma unroll
    for (int tt = 0; tt < 4; tt++) {
      floatx4 sc[4];
#pragma unroll
      for (int st = 0; st < 4; st++) {
        floatx4 a = {};
        a = __builtin_amdgcn_mfma_f32_16x16x32_bf16(kf[st][0], qf[tt][0], a, 0, 0, 0);
        a = __builtin_amdgcn_mfma_f32_16x16x32_bf16(kf[st][1], qf[tt][1], a, 0, 0, 0);
        sc[st] = a;
      }
      // P^T = exp2(S^T): 4 regs = consecutive s-cols of row t=ln -> b64 write
#pragma unroll
      for (int st = 0; st < 4; st++) {
        uint2v u;
        u.x = pk2bf(exp2f(sc[st][0]), exp2f(sc[st][1]));
        u.y = pk2bf(exp2f(sc[st][2]), exp2f(sc[st][3]));
        *(uint2v*)&Pb[wv][ln][st * 16 + quad * 4] = u;
      }
      // P @ V (same-wave in-order LDS: read sees this wave's writes)
#pragma unroll
      for (int kc = 0; kc < 2; kc++) {
        short8 pf = *(const short8*)&Pb[wv][ln][kc * 32 + quad * 8];
#pragma unroll
        for (int di = 0; di < 4; di++)
          Oa[tt][di] = __builtin_amdgcn_mfma_f32_16x16x32_bf16(vf[di][kc], pf, Oa[tt][di], 0, 0, 0);
        Ol[tt] = __builtin_amdgcn_mfma_f32_16x16x32_bf16(onesf, pf, Ol[tt], 0, 0, 0);
      }
    }
  }

  // epilogue: O^T[d = di*16+quad*4+r][t = ln] per subtile
#pragma unroll
  for (int tt = 0; tt < 4; tt++) {
    float linv = 1.0f / Ol[tt][0];
    size_t rowbase = (size_t)(b * SEQ + tb + tt * 64 + wv * 16 + ln) * EMB + h * HD;
#pragma unroll
    for (int di = 0; di < 4; di++) {
      uint2v pkt;
      pkt.x = pk2bf(Oa[tt][di][0] * linv, Oa[tt][di][1] * linv);
      pkt.y = pk2bf(Oa[tt][di][2] * linv, Oa[tt][di][3] * linv);
      *(uint2v*)&o[rowbase + di * 16 + quad * 4] = pkt;
    }
  }
}

// ---------------- launch --------------------------------------------------
extern "C" void kernel_launch(void* const* d_in, const int* in_sizes, int n_in,
                              void* d_out, int out_size, void* d_ws, size_t ws_size,
                              hipStream_t stream) {
  const float* query = (const float*)d_in[0];
  const float* key   = (const float*)d_in[1];
  const float* value = (const float*)d_in[2];
  const float* Wq = (const float*)d_in[3];
  const float* bq = (const float*)d_in[4];
  const float* Wk = (const float*)d_in[5];
  const float* bk = (const float*)d_in[6];
  const float* Wv = (const float*)d_in[7];
  const float* bv = (const float*)d_in[8];
  const float* Wo = (const float*)d_in[9];
  const float* bo = (const float*)d_in[10];
  float* out = (float*)d_out;

  unsigned short* ws = (unsigned short*)d_ws;
  const size_t WSZ = (size_t)EMB * EMB;     // 1M elems
  const size_t TSZ = (size_t)MROWS * EMB;   // 8M elems
  unsigned short* Wb   = ws;                // [4][N][K] bf16 (q,k,v,o)
  unsigned short* q_b  = Wb + 4 * WSZ;      // qkv outputs contiguous (z-indexed)
  unsigned short* k_b  = q_b + TSZ;
  unsigned short* vt_b = k_b + TSZ;
  unsigned short* o_b  = vt_b + TSZ;

  const float qscale = 0.125f * LOG2E;      // head_dim^-0.5 * log2(e)

  convert_w4<<<dim3((int)(WSZ / 4 / 256), 4), 256, 0, stream>>>(Wq, Wk, Wv, Wo, Wb, qscale);

  gemm_k<1><<<dim3(8 * 64 * 3), 256, 0, stream>>>(
      query, key, value, (const unsigned short*)0, Wb,
      bq, bk, bv, qscale, q_b, (float*)0);

  attn_k<<<dim3(BSZ * NH * (SEQ / 256)), 256, 0, stream>>>(q_b, k_b, vt_b, o_b);

  gemm_k<0><<<dim3(8 * 64), 256, 0, stream>>>(
      (const float*)0, (const float*)0, (const float*)0, o_b, Wb + 3 * WSZ,
      bo, (const float*)0, (const float*)0, 1.0f, (unsigned short*)0, out);
}